// Round 2
// baseline (382.475 us; speedup 1.0000x reference)
//
#include <hip/hip_runtime.h>
#include <hip/hip_bf16.h>
#include <stdint.h>

// Problem constants
constexpr int S_ = 2048, H_ = 32, G_ = 8, HPG_ = 4, D_ = 128, MODEL_ = 4096;

typedef __attribute__((ext_vector_type(4))) float f32x4;
typedef __attribute__((ext_vector_type(8))) short bf16x8;
typedef __attribute__((ext_vector_type(4))) short bf16x4;

__device__ inline unsigned short f2bf(float f) {
  unsigned u = __float_as_uint(f);
  u += 0x7FFFu + ((u >> 16) & 1u);   // round-to-nearest-even
  return (unsigned short)(u >> 16);
}

__device__ inline void gload_lds16(const void* g, void* l) {
  __builtin_amdgcn_global_load_lds(
      (const __attribute__((address_space(1))) unsigned int*)g,
      (__attribute__((address_space(3))) unsigned int*)l,
      16, 0, 0);
}

// ---------------- w_out f32 -> bf16 prepass ----------------
__global__ __launch_bounds__(256) void cvt_f32_to_bf16(
    const float* __restrict__ in, unsigned short* __restrict__ out, int n4) {
  int i = blockIdx.x * 256 + threadIdx.x;
  if (i < n4) {
    float4 v = reinterpret_cast<const float4*>(in)[i];
    bf16x4 o;
    o[0] = f2bf(v.x); o[1] = f2bf(v.y); o[2] = f2bf(v.z); o[3] = f2bf(v.w);
    reinterpret_cast<bf16x4*>(out)[i] = o;
  }
}

// ---------------- flash attention ----------------
// grid: (S/64, H). 4 waves/block; wave w owns q-rows [qt*64+w*16, +16).
// Q pre-scaled by D^-0.5, kept in registers as MFMA A-frags.
// K tile [32][128] bf16 in LDS, XOR-swizzled (G4: row-major D=128 conflicts).
// V tile stored TRANSPOSED Vt[d][kv], row stride 40 elems (80B, 16B-aligned).
// P re-layout D-frag -> A-frag through per-wave LDS ([16][40] bf16).
constexpr int QBLK = 64, KVBLK = 32;

__global__ __launch_bounds__(256, 2) void attn_kernel(
    const float* __restrict__ q, const float* __restrict__ k,
    const float* __restrict__ v, unsigned short* __restrict__ aout) {
  __shared__ unsigned short Ks[KVBLK * 128];   // swizzled row-major
  __shared__ unsigned short Vt[128 * 40];      // [d][kv], pad to 40
  __shared__ unsigned short Pl[4][16 * 40];    // per-wave P, pad to 40

  const int qt = blockIdx.x, h = blockIdx.y;
  const int g = h / HPG_;
  const int tid = threadIdx.x;
  const int w = tid >> 6, lane = tid & 63;
  const int r16 = lane & 15, g4 = lane >> 4;

  // ---- load Q fragments (scaled) ----
  const float scale = 0.08838834764831845f;  // 1/sqrt(128)
  bf16x8 qf[4];
  {
    const int qrow = qt * QBLK + w * 16 + r16;
    const float* qp = q + (size_t)qrow * (H_ * D_) + h * D_ + g4 * 8;
#pragma unroll
    for (int c = 0; c < 4; ++c) {
      float4 a = *(const float4*)(qp + c * 32);
      float4 b = *(const float4*)(qp + c * 32 + 4);
      bf16x8 f;
      f[0] = f2bf(a.x * scale); f[1] = f2bf(a.y * scale);
      f[2] = f2bf(a.z * scale); f[3] = f2bf(a.w * scale);
      f[4] = f2bf(b.x * scale); f[5] = f2bf(b.y * scale);
      f[6] = f2bf(b.z * scale); f[7] = f2bf(b.w * scale);
      qf[c] = f;
    }
  }

  f32x4 of[8];
#pragma unroll
  for (int i = 0; i < 8; ++i) of[i] = (f32x4)0.f;
  float mrow[4], lrow[4];
#pragma unroll
  for (int i = 0; i < 4; ++i) { mrow[i] = -1e30f; lrow[i] = 0.f; }

  for (int t = 0; t < S_ / KVBLK; ++t) {
    const int kv0 = t * KVBLK;
    __syncthreads();  // all waves done reading previous K/V tiles
    // ---- stage K (swizzled) ----
    {
      const float* kbase = k + (size_t)kv0 * (G_ * D_) + g * D_;
#pragma unroll
      for (int cc = 0; cc < 4; ++cc) {
        int e = cc * 1024 + tid * 4;  // element index in [32][128]
        int row = e >> 7, col = e & 127;
        float4 kv4 = *(const float4*)(kbase + (size_t)row * (G_ * D_) + col);
        unsigned byteoff = ((unsigned)(row * 256 + col * 2)) ^ ((row & 7) << 4);
        bf16x4 kb;
        kb[0] = f2bf(kv4.x); kb[1] = f2bf(kv4.y);
        kb[2] = f2bf(kv4.z); kb[3] = f2bf(kv4.w);
        *(bf16x4*)((char*)Ks + byteoff) = kb;
      }
      // ---- stage V transposed: coalesced scalar reads, b64 writes along kv ----
      const float* vbase = v + (size_t)kv0 * (G_ * D_) + g * D_;
#pragma unroll
      for (int pp = 0; pp < 4; ++pp) {
        int idx = pp * 256 + tid;       // 0..1023
        int d = idx & 127, kvq = idx >> 7;  // kv quad 0..7
        bf16x4 vb;
#pragma unroll
        for (int jj = 0; jj < 4; ++jj)
          vb[jj] = f2bf(vbase[(size_t)(kvq * 4 + jj) * (G_ * D_) + d]);
        *(bf16x4*)(&Vt[d * 40 + kvq * 4]) = vb;
      }
    }
    __syncthreads();

    // ---- QK^T: 2 col-blocks x 4 d-chunks ----
    f32x4 sacc[2];
    sacc[0] = (f32x4)0.f; sacc[1] = (f32x4)0.f;
#pragma unroll
    for (int cb = 0; cb < 2; ++cb) {
      int krow = cb * 16 + r16;
#pragma unroll
      for (int c = 0; c < 4; ++c) {
        // full logical byte address, THEN xor-swizzle (bits 4..6 overlap!)
        unsigned off = ((unsigned)(krow * 256 + (c * 32 + g4 * 8) * 2)) ^
                       ((unsigned)(krow & 7) << 4);
        bf16x8 kf = *(bf16x8*)((char*)Ks + off);
        sacc[cb] = __builtin_amdgcn_mfma_f32_16x16x32_bf16(qf[c], kf, sacc[cb], 0, 0, 0);
      }
    }

    // ---- online softmax (wave-parallel, rows live in 16-lane groups) ----
    float alpha[4];
#pragma unroll
    for (int j = 0; j < 4; ++j) {
      float mx = fmaxf(sacc[0][j], sacc[1][j]);
#pragma unroll
      for (int o = 1; o < 16; o <<= 1) mx = fmaxf(mx, __shfl_xor(mx, o, 64));
      float mnew = fmaxf(mrow[j], mx);
      alpha[j] = __expf(mrow[j] - mnew);
      float p0 = __expf(sacc[0][j] - mnew);
      float p1 = __expf(sacc[1][j] - mnew);
      float sum = p0 + p1;
#pragma unroll
      for (int o = 1; o < 16; o <<= 1) sum += __shfl_xor(sum, o, 64);
      lrow[j] = lrow[j] * alpha[j] + sum;
      mrow[j] = mnew;
      int prow = g4 * 4 + j;
      Pl[w][prow * 40 + r16] = f2bf(p0);
      Pl[w][prow * 40 + 16 + r16] = f2bf(p1);
    }
#pragma unroll
    for (int db = 0; db < 8; ++db) {
#pragma unroll
      for (int j = 0; j < 4; ++j) of[db][j] *= alpha[j];
    }

    // ---- PV: read P as A-frag, Vt rows as B-frags ----
    bf16x8 pf = *(bf16x8*)((char*)&Pl[w][0] + (r16 * 40 + g4 * 8) * 2);
#pragma unroll
    for (int db = 0; db < 8; ++db) {
      bf16x8 vf = *(bf16x8*)(&Vt[(db * 16 + r16) * 40 + g4 * 8]);
      of[db] = __builtin_amdgcn_mfma_f32_16x16x32_bf16(pf, vf, of[db], 0, 0, 0);
    }
  }

  // ---- epilogue: normalize, store bf16 into attn workspace [S][MODEL] ----
  const int qrow0 = qt * QBLK + w * 16;
#pragma unroll
  for (int j = 0; j < 4; ++j) {
    float inv = 1.0f / lrow[j];
    int r = g4 * 4 + j;
    size_t base = (size_t)(qrow0 + r) * MODEL_ + h * D_;
#pragma unroll
    for (int db = 0; db < 8; ++db)
      aout[base + db * 16 + r16] = f2bf(of[db][j] * inv);
  }
}

// ---------------- out-projection GEMM: C = A @ B^T + bias ----------------
// A = attn bf16 [2048][4096], B = w_out bf16 [4096][4096], C f32 [2048][4096].
// m97 structure: 128x128 tile, BK=64, 4 waves (2x2), global_load_lds w=16,
// pre-swizzled source + XOR-swizzled ds_read_b128.
constexpr int BM = 128, BN = 128, BK = 64;

__global__ __launch_bounds__(256, 2) void gemm_bt_bias(
    const unsigned short* __restrict__ A, const unsigned short* __restrict__ B,
    const float* __restrict__ bias, float* __restrict__ C) {
  __shared__ unsigned short As[BM * BK];
  __shared__ unsigned short Bs[BN * BK];

  const int tid = threadIdx.x;
  const int w = tid >> 6, lane = tid & 63;
  const int wr = w >> 1, wc = w & 1;
  const int r16 = lane & 15, g4 = lane >> 4;
  const int row0 = blockIdx.y * BM, col0 = blockIdx.x * BN;

  f32x4 acc[4][4];
#pragma unroll
  for (int m = 0; m < 4; ++m)
#pragma unroll
    for (int n = 0; n < 4; ++n) acc[m][n] = (f32x4)0.f;

  for (int kt = 0; kt < MODEL_ / BK; ++kt) {
    const int k0 = kt * BK;
    __syncthreads();  // everyone done reading previous tile
    // stage A,B: 16 wave-chunks of 1KB each per tile; source pre-swizzled so
    // that swizzled reads (byte ^ (row&7)<<4) see linear data.
#pragma unroll
    for (int j = 0; j < 4; ++j) {
      int chunk = w * 4 + j;
      int sb = chunk * 1024 + lane * 16;     // phys byte in tile
      int srow = sb >> 7;                    // row (128B rows)
      int lb = sb ^ ((srow & 7) << 4);       // logical byte
      int kk = (lb & 127) >> 1;              // logical k element
      gload_lds16(A + (size_t)(row0 + srow) * MODEL_ + k0 + kk,
                  (char*)As + chunk * 1024);
      gload_lds16(B + (size_t)(col0 + srow) * MODEL_ + k0 + kk,
                  (char*)Bs + chunk * 1024);
    }
    asm volatile("s_waitcnt vmcnt(0)" ::: "memory");
    __syncthreads();

#pragma unroll
    for (int kc = 0; kc < 2; ++kc) {
      bf16x8 af[4], bfr[4];
#pragma unroll
      for (int m = 0; m < 4; ++m) {
        int row = wr * 64 + m * 16 + r16;
        unsigned off = ((unsigned)(row * 128 + (kc * 32 + g4 * 8) * 2)) ^ ((row & 7) << 4);
        af[m] = *(bf16x8*)((char*)As + off);
      }
#pragma unroll
      for (int n = 0; n < 4; ++n) {
        int row = wc * 64 + n * 16 + r16;
        unsigned off = ((unsigned)(row * 128 + (kc * 32 + g4 * 8) * 2)) ^ ((row & 7) << 4);
        bfr[n] = *(bf16x8*)((char*)Bs + off);
      }
#pragma unroll
      for (int m = 0; m < 4; ++m)
#pragma unroll
        for (int n = 0; n < 4; ++n)
          acc[m][n] = __builtin_amdgcn_mfma_f32_16x16x32_bf16(af[m], bfr[n], acc[m][n], 0, 0, 0);
    }
  }

  // epilogue: C = acc + bias (f32 direct to d_out)
#pragma unroll
  for (int n = 0; n < 4; ++n) {
    int col = col0 + wc * 64 + n * 16 + r16;
    float bv = bias[col];
#pragma unroll
    for (int m = 0; m < 4; ++m) {
      int rbase = row0 + wr * 64 + m * 16 + g4 * 4;
#pragma unroll
      for (int j = 0; j < 4; ++j)
        C[(size_t)(rbase + j) * MODEL_ + col] = acc[m][n][j] + bv;
    }
  }
}

extern "C" void kernel_launch(void* const* d_in, const int* in_sizes, int n_in,
                              void* d_out, int out_size, void* d_ws, size_t ws_size,
                              hipStream_t stream) {
  const float* q = (const float*)d_in[0];
  const float* k = (const float*)d_in[1];
  const float* v = (const float*)d_in[2];
  // d_in[3] = mask: faithfully unused (reference never applies it)
  const float* w_out = (const float*)d_in[4];
  const float* b_out = (const float*)d_in[5];
  float* out = (float*)d_out;

  unsigned short* attn_bf = (unsigned short*)d_ws;                 // 16.78 MB
  unsigned short* w_bf = attn_bf + (size_t)S_ * MODEL_;            // 33.55 MB
  if (ws_size < ((size_t)S_ * MODEL_ + (size_t)MODEL_ * MODEL_) * 2) return;

  cvt_f32_to_bf16<<<(MODEL_ * MODEL_ / 4) / 256, 256, 0, stream>>>(
      w_out, w_bf, MODEL_ * MODEL_ / 4);

  dim3 ag(S_ / QBLK, H_);
  attn_kernel<<<ag, 256, 0, stream>>>(q, k, v, attn_bf);

  dim3 gg(MODEL_ / BN, S_ / BM);
  gemm_bt_bias<<<gg, 256, 0, stream>>>(attn_bf, w_bf, b_out, out);
}

// Round 3
// 193.342 us; speedup vs baseline: 1.9782x; 1.9782x over previous
//
#include <hip/hip_runtime.h>
#include <hip/hip_bf16.h>
#include <stdint.h>

// Problem constants
constexpr int S_ = 2048, H_ = 32, G_ = 8, HPG_ = 4, D_ = 128, MODEL_ = 4096;

typedef __attribute__((ext_vector_type(4))) float f32x4;
typedef __attribute__((ext_vector_type(16))) float f32x16;
typedef __attribute__((ext_vector_type(8))) short bf16x8;
typedef __attribute__((ext_vector_type(4))) short bf16x4;

__device__ inline unsigned short f2bf(float f) {
  unsigned u = __float_as_uint(f);
  u += 0x7FFFu + ((u >> 16) & 1u);   // round-to-nearest-even
  return (unsigned short)(u >> 16);
}

__device__ inline void gload_lds16(const void* g, void* l) {
  __builtin_amdgcn_global_load_lds(
      (const __attribute__((address_space(1))) unsigned int*)g,
      (__attribute__((address_space(3))) unsigned int*)l,
      16, 0, 0);
}

// ---------------- w_out f32 -> bf16 (runs AFTER attn; aliases k/v region) ---
__global__ __launch_bounds__(256) void cvt_f32_to_bf16(
    const float* __restrict__ in, unsigned short* __restrict__ out, int n4) {
  int i = blockIdx.x * 256 + threadIdx.x;
  if (i < n4) {
    float4 v = reinterpret_cast<const float4*>(in)[i];
    bf16x4 o;
    o[0] = f2bf(v.x); o[1] = f2bf(v.y); o[2] = f2bf(v.z); o[3] = f2bf(v.w);
    reinterpret_cast<bf16x4*>(out)[i] = o;
  }
}

// ---------------- K: [S][G][D] f32 -> [G][S][D] bf16 ----------------
__global__ __launch_bounds__(256) void cvt_k_kernel(
    const float* __restrict__ in, unsigned short* __restrict__ out) {
  int i = blockIdx.x * 256 + threadIdx.x;   // over S*G*D/4
  int d4 = i & 31, g = (i >> 5) & 7, s = i >> 8;
  float4 v = reinterpret_cast<const float4*>(in)[i];
  bf16x4 o;
  o[0] = f2bf(v.x); o[1] = f2bf(v.y); o[2] = f2bf(v.z); o[3] = f2bf(v.w);
  reinterpret_cast<bf16x4*>(out)[(g * S_ + s) * 32 + d4] = o;
}

// ---------------- V: [S][G][D] f32 -> [G][D][S] bf16 (transpose) -----------
__global__ __launch_bounds__(256) void cvt_v_kernel(
    const float* __restrict__ in, unsigned short* __restrict__ out) {
  __shared__ float t[64][33];
  int s0 = blockIdx.x * 64, d0 = blockIdx.y * 32, g = blockIdx.z;
  int tid = threadIdx.x;
#pragma unroll
  for (int p = 0; p < 2; ++p) {
    int idx = p * 256 + tid;
    int s = idx >> 3, dq = (idx & 7) * 4;
    float4 v = *reinterpret_cast<const float4*>(
        in + ((size_t)(s0 + s) * G_ + g) * D_ + d0 + dq);
    t[s][dq] = v.x; t[s][dq + 1] = v.y; t[s][dq + 2] = v.z; t[s][dq + 3] = v.w;
  }
  __syncthreads();
  int d = tid >> 3, sq = (tid & 7) * 8;
  bf16x8 o;
#pragma unroll
  for (int j = 0; j < 8; ++j) o[j] = f2bf(t[sq + j][d]);
  *reinterpret_cast<bf16x8*>(out + ((size_t)g * D_ + d0 + d) * S_ + s0 + sq) = o;
}

// ---------------- flash attention, 32x32 MFMA, swapped operands ----------------
// grid (S/128, H), 4 waves/block, wave owns 32 q-rows (lane&31 = q).
// S^T[kv][q] = K·Q^T  (A = K from LDS, B = Q in regs)
// O^T[d][q] += Vt·P^T (A = Vt from LDS, B = P in regs via permlane32_swap)
constexpr int QB2 = 128, KVB = 32;
constexpr float RTHR = 8.0f;   // defer-max threshold (T13)

__global__ __launch_bounds__(256, 2) void attn32_kernel(
    const float* __restrict__ q, const unsigned short* __restrict__ kb,
    const unsigned short* __restrict__ vtb, unsigned short* __restrict__ aout) {
  // Ks0 @0 (8KB) | Vt0 @8192 | Ks1 @16384 | Vt1 @24576 ; epilogue reuses all 32KB
  __shared__ __align__(16) char smem[32768];

  const int qt = blockIdx.x, h = blockIdx.y;
  const int g = h >> 2;   // HPG = 4
  const int tid = threadIdx.x, w = tid >> 6, lane = tid & 63;
  const int l31 = lane & 31, hi = lane >> 5;

  // ---- Q B-frags (scaled, cvt once per block): qf[c] d = c*16 + hi*8 + e ----
  const float scale = 0.08838834764831845f;
  bf16x8 qf[8];
  const int qrow = qt * QB2 + w * 32 + l31;
  {
    const float* qp = q + ((size_t)qrow * H_ + h) * D_;
#pragma unroll
    for (int c = 0; c < 8; ++c) {
      const float* p0 = qp + c * 16 + hi * 8;
      float4 a = *(const float4*)p0;
      float4 b = *(const float4*)(p0 + 4);
      bf16x8 f;
      f[0] = f2bf(a.x * scale); f[1] = f2bf(a.y * scale);
      f[2] = f2bf(a.z * scale); f[3] = f2bf(a.w * scale);
      f[4] = f2bf(b.x * scale); f[5] = f2bf(b.y * scale);
      f[6] = f2bf(b.z * scale); f[7] = f2bf(b.w * scale);
      qf[c] = f;
    }
  }

  // ---- staging source precompute (pre-swizzled so linear LDS == swizzled) ----
  // K phys byte p: row kv = p>>8, logical col byte = (p&255) ^ ((kv&7)<<4)
  // V phys byte p: row d  = p>>6, logical col byte = (p&63)  ^ ((d&3)<<4)
  int ks_kv[2], ks_d[2], vs_d[2], vs_kv[2];
#pragma unroll
  for (int hh = 0; hh < 2; ++hh) {
    int p = w * 1024 + hh * 4096 + lane * 16;
    int kvr = p >> 8;
    ks_kv[hh] = kvr;
    ks_d[hh] = ((p & 255) ^ ((kvr & 7) << 4)) >> 1;
    int dr = p >> 6;
    vs_d[hh] = dr;
    vs_kv[hh] = ((p & 63) ^ ((dr & 3) << 4)) >> 1;
  }
  const unsigned short* kg = kb + (size_t)g * S_ * D_;
  const unsigned short* vg = vtb + (size_t)g * D_ * S_;

  auto stage = [&](int t, int buf) {
    int kv0 = t * KVB;
    char* Kd = smem + buf * 16384;
    char* Vd = smem + buf * 16384 + 8192;
#pragma unroll
    for (int hh = 0; hh < 2; ++hh) {
      gload_lds16(kg + (size_t)(kv0 + ks_kv[hh]) * D_ + ks_d[hh],
                  Kd + w * 1024 + hh * 4096);
      gload_lds16(vg + (size_t)vs_d[hh] * S_ + kv0 + vs_kv[hh],
                  Vd + w * 1024 + hh * 4096);
    }
  };

  f32x16 of[4];
#pragma unroll
  for (int i = 0; i < 4; ++i) of[i] = (f32x16)0.f;
  float m = -1e30f, l = 0.f;

  stage(0, 0);
  asm volatile("s_waitcnt vmcnt(0)" ::: "memory");
  __syncthreads();

  for (int t = 0; t < S_ / KVB; ++t) {
    const int buf = t & 1;
    if (t + 1 < S_ / KVB) stage(t + 1, buf ^ 1);
    const char* Kd = smem + buf * 16384;
    const char* Vd = smem + buf * 16384 + 8192;

    // ---- QK^T: S^T[kv][q], two independent 4-chains ----
    f32x16 s0 = (f32x16)0.f, s1 = (f32x16)0.f;
#pragma unroll
    for (int c = 0; c < 8; ++c) {
      unsigned off = ((unsigned)(l31 * 256 + c * 32 + hi * 16)) ^
                     ((unsigned)(l31 & 7) << 4);
      bf16x8 kf = *(const bf16x8*)(Kd + off);
      if (c & 1)
        s1 = __builtin_amdgcn_mfma_f32_32x32x16_bf16(kf, qf[c], s1, 0, 0, 0);
      else
        s0 = __builtin_amdgcn_mfma_f32_32x32x16_bf16(kf, qf[c], s0, 0, 0, 0);
    }
    f32x16 sv = s0 + s1;   // S rows: kv = (r&3) + 8*(r>>2) + 4*hi; col q = l31

    // ---- online softmax (per-lane q; halves share q via lane^32) ----
    float tmax = sv[0];
#pragma unroll
    for (int r = 1; r < 16; ++r) tmax = fmaxf(tmax, sv[r]);
    tmax = fmaxf(tmax, __shfl_xor(tmax, 32));
    if (__any(tmax > m + RTHR)) {
      float mnew = fmaxf(m, tmax);
      float alpha = __expf(m - mnew);
#pragma unroll
      for (int i = 0; i < 4; ++i)
#pragma unroll
        for (int r = 0; r < 16; ++r) of[i][r] *= alpha;
      l *= alpha;
      m = mnew;
    }
    float pv[16];
    float sum = 0.f;
#pragma unroll
    for (int r = 0; r < 16; ++r) { pv[r] = __expf(sv[r] - m); sum += pv[r]; }
    sum += __shfl_xor(sum, 32);
    l += sum;

    // ---- P -> B-frags: pack bf16 pairs, permlane32_swap gathers lows/highs ----
    unsigned pk[8];
#pragma unroll
    for (int b = 0; b < 8; ++b)
      pk[b] = ((unsigned)f2bf(pv[2 * b + 1]) << 16) | f2bf(pv[2 * b]);
    bf16x8 pf[2];
#pragma unroll
    for (int kc = 0; kc < 2; ++kc) {
      // swap(x,y): res0 = concat(x_lo, y_lo), res1 = concat(x_hi, y_hi)
      auto sA = __builtin_amdgcn_permlane32_swap(pk[kc * 4 + 0], pk[kc * 4 + 2],
                                                 false, false);
      auto sB = __builtin_amdgcn_permlane32_swap(pk[kc * 4 + 1], pk[kc * 4 + 3],
                                                 false, false);
      unsigned fr[4] = {(unsigned)sA[0], (unsigned)sB[0],
                        (unsigned)sA[1], (unsigned)sB[1]};
      __builtin_memcpy(&pf[kc], fr, 16);
    }

    // ---- PV: O^T[d][q] += Vt·P^T, 4 independent chains ----
#pragma unroll
    for (int db = 0; db < 4; ++db) {
      int d = db * 32 + l31;
#pragma unroll
      for (int kc = 0; kc < 2; ++kc) {
        unsigned off = ((unsigned)(d * 64 + kc * 32 + hi * 16)) ^
                       ((unsigned)(d & 3) << 4);
        bf16x8 vf = *(const bf16x8*)(Vd + off);
        of[db] = __builtin_amdgcn_mfma_f32_32x32x16_bf16(vf, pf[kc], of[db], 0, 0, 0);
      }
    }
    asm volatile("s_waitcnt vmcnt(0)" ::: "memory");
    __syncthreads();
  }

  // ---- epilogue: normalize, transpose via LDS, coalesced bf16 store ----
  float inv = 1.0f / l;
  unsigned short* Ol = (unsigned short*)smem;   // [128 q][128 d] bf16 = 32KB
  const int ql = w * 32 + l31;
#pragma unroll
  for (int db = 0; db < 4; ++db) {
#pragma unroll
    for (int rp = 0; rp < 8; ++rp) {
      int r0 = rp * 2;
      int d0 = db * 32 + (r0 & 3) + 8 * (r0 >> 2) + 4 * hi;  // d0 even, d0+1 next
      unsigned pkv = ((unsigned)f2bf(of[db][r0 + 1] * inv) << 16) |
                     f2bf(of[db][r0] * inv);
      unsigned off = ((unsigned)(ql * 256 + d0 * 2)) ^ ((unsigned)(ql & 7) << 4);
      *(unsigned*)((char*)Ol + off) = pkv;
    }
  }
  __syncthreads();
  const size_t obase = ((size_t)qt * QB2) * MODEL_ + (size_t)h * D_;
#pragma unroll
  for (int pass = 0; pass < 8; ++pass) {
    int row = pass * 16 + (tid >> 4);
    int c = tid & 15;
    unsigned off = ((unsigned)(row * 256 + c * 16)) ^ ((unsigned)(row & 7) << 4);
    bf16x8 vv = *(const bf16x8*)((char*)Ol + off);
    *(bf16x8*)(aout + obase + (size_t)row * MODEL_ + c * 8) = vv;
  }
}

// ---------------- out-projection GEMM: C = A @ B^T + bias (m97 structure) ----
constexpr int BM = 128, BN = 128, BK = 64;

__global__ __launch_bounds__(256, 2) void gemm_bt_bias(
    const unsigned short* __restrict__ A, const unsigned short* __restrict__ B,
    const float* __restrict__ bias, float* __restrict__ C) {
  __shared__ unsigned short As[BM * BK];
  __shared__ unsigned short Bs[BN * BK];

  const int tid = threadIdx.x;
  const int w = tid >> 6, lane = tid & 63;
  const int wr = w >> 1, wc = w & 1;
  const int r16 = lane & 15, g4 = lane >> 4;
  const int row0 = blockIdx.y * BM, col0 = blockIdx.x * BN;

  f32x4 acc[4][4];
#pragma unroll
  for (int m = 0; m < 4; ++m)
#pragma unroll
    for (int n = 0; n < 4; ++n) acc[m][n] = (f32x4)0.f;

  for (int kt = 0; kt < MODEL_ / BK; ++kt) {
    const int k0 = kt * BK;
    __syncthreads();
#pragma unroll
    for (int j = 0; j < 4; ++j) {
      int chunk = w * 4 + j;
      int sb = chunk * 1024 + lane * 16;
      int srow = sb >> 7;
      int lb = sb ^ ((srow & 7) << 4);
      int kk = (lb & 127) >> 1;
      gload_lds16(A + (size_t)(row0 + srow) * MODEL_ + k0 + kk,
                  (char*)As + chunk * 1024);
      gload_lds16(B + (size_t)(col0 + srow) * MODEL_ + k0 + kk,
                  (char*)Bs + chunk * 1024);
    }
    asm volatile("s_waitcnt vmcnt(0)" ::: "memory");
    __syncthreads();

#pragma unroll
    for (int kc = 0; kc < 2; ++kc) {
      bf16x8 af[4], bfr[4];
#pragma unroll
      for (int m = 0; m < 4; ++m) {
        int row = wr * 64 + m * 16 + r16;
        unsigned off = ((unsigned)(row * 128 + (kc * 32 + g4 * 8) * 2)) ^ ((row & 7) << 4);
        af[m] = *(bf16x8*)((char*)As + off);
      }
#pragma unroll
      for (int n = 0; n < 4; ++n) {
        int row = wc * 64 + n * 16 + r16;
        unsigned off = ((unsigned)(row * 128 + (kc * 32 + g4 * 8) * 2)) ^ ((row & 7) << 4);
        bfr[n] = *(bf16x8*)((char*)Bs + off);
      }
#pragma unroll
      for (int m = 0; m < 4; ++m)
#pragma unroll
        for (int n = 0; n < 4; ++n)
          acc[m][n] = __builtin_amdgcn_mfma_f32_16x16x32_bf16(af[m], bfr[n], acc[m][n], 0, 0, 0);
    }
  }

#pragma unroll
  for (int n = 0; n < 4; ++n) {
    int col = col0 + wc * 64 + n * 16 + r16;
    float bv = bias[col];
#pragma unroll
    for (int m = 0; m < 4; ++m) {
      int rbase = row0 + wr * 64 + m * 16 + g4 * 4;
#pragma unroll
      for (int j = 0; j < 4; ++j)
        C[(size_t)(rbase + j) * MODEL_ + col] = acc[m][n][j] + bv;
    }
  }
}

extern "C" void kernel_launch(void* const* d_in, const int* in_sizes, int n_in,
                              void* d_out, int out_size, void* d_ws, size_t ws_size,
                              hipStream_t stream) {
  const float* q = (const float*)d_in[0];
  const float* k = (const float*)d_in[1];
  const float* v = (const float*)d_in[2];
  // d_in[3] = mask: faithfully unused (reference never applies it)
  const float* w_out = (const float*)d_in[4];
  const float* b_out = (const float*)d_in[5];
  float* out = (float*)d_out;

  // ws layout: [attn_bf 16.78MB][X region 33.55MB]
  //   X holds k_bf(4MB)+vt_bf(4MB) during attention, then w_bf (cvt AFTER attn).
  unsigned short* attn_bf = (unsigned short*)d_ws;
  unsigned short* xreg = attn_bf + (size_t)S_ * MODEL_;
  unsigned short* k_bf = xreg;
  unsigned short* vt_bf = xreg + (size_t)G_ * S_ * D_;
  unsigned short* w_bf = xreg;
  if (ws_size < ((size_t)S_ * MODEL_ + (size_t)MODEL_ * MODEL_) * 2) return;

  cvt_k_kernel<<<S_ * G_ * D_ / 4 / 256, 256, 0, stream>>>(k, k_bf);
  dim3 vg(S_ / 64, D_ / 32, G_);
  cvt_v_kernel<<<vg, 256, 0, stream>>>(v, vt_bf);

  dim3 ag(S_ / QB2, H_);
  attn32_kernel<<<ag, 256, 0, stream>>>(q, k_bf, vt_bf, attn_bf);

  cvt_f32_to_bf16<<<(MODEL_ * MODEL_ / 4) / 256, 256, 0, stream>>>(
      w_out, w_bf, MODEL_ * MODEL_ / 4);

  dim3 gg(MODEL_ / BN, S_ / BM);
  gemm_bt_bias<<<gg, 256, 0, stream>>>(attn_bf, w_bf, b_out, out);
}

// Round 4
// 185.497 us; speedup vs baseline: 2.0619x; 1.0423x over previous
//
#include <hip/hip_runtime.h>
#include <hip/hip_bf16.h>
#include <stdint.h>

// Problem constants
constexpr int S_ = 2048, H_ = 32, G_ = 8, HPG_ = 4, D_ = 128, MODEL_ = 4096;

typedef __attribute__((ext_vector_type(4))) float f32x4;
typedef __attribute__((ext_vector_type(16))) float f32x16;
typedef __attribute__((ext_vector_type(8))) short bf16x8;
typedef __attribute__((ext_vector_type(4))) short bf16x4;

__device__ inline unsigned short f2bf(float f) {
  unsigned u = __float_as_uint(f);
  u += 0x7FFFu + ((u >> 16) & 1u);   // round-to-nearest-even
  return (unsigned short)(u >> 16);
}

__device__ inline unsigned cvt_pk_bf16(float lo, float hi) {
  unsigned r;
  asm("v_cvt_pk_bf16_f32 %0, %1, %2" : "=v"(r) : "v"(lo), "v"(hi));
  return r;
}

__device__ inline void gload_lds16(const void* g, void* l) {
  __builtin_amdgcn_global_load_lds(
      (const __attribute__((address_space(1))) unsigned int*)g,
      (__attribute__((address_space(3))) unsigned int*)l,
      16, 0, 0);
}

// ---------------- w_out f32 -> bf16 (runs AFTER attn; aliases k/v region) ---
__global__ __launch_bounds__(256) void cvt_f32_to_bf16(
    const float* __restrict__ in, unsigned short* __restrict__ out, int n4) {
  int i = blockIdx.x * 256 + threadIdx.x;
  if (i < n4) {
    float4 v = reinterpret_cast<const float4*>(in)[i];
    bf16x4 o;
    o[0] = f2bf(v.x); o[1] = f2bf(v.y); o[2] = f2bf(v.z); o[3] = f2bf(v.w);
    reinterpret_cast<bf16x4*>(out)[i] = o;
  }
}

// ---------------- K: [S][G][D] f32 -> [G][S][D] bf16 ----------------
__global__ __launch_bounds__(256) void cvt_k_kernel(
    const float* __restrict__ in, unsigned short* __restrict__ out) {
  int i = blockIdx.x * 256 + threadIdx.x;   // over S*G*D/4
  int d4 = i & 31, g = (i >> 5) & 7, s = i >> 8;
  float4 v = reinterpret_cast<const float4*>(in)[i];
  bf16x4 o;
  o[0] = f2bf(v.x); o[1] = f2bf(v.y); o[2] = f2bf(v.z); o[3] = f2bf(v.w);
  reinterpret_cast<bf16x4*>(out)[(g * S_ + s) * 32 + d4] = o;
}

// ---------------- V: [S][G][D] f32 -> [G][D][S] bf16 (transpose) -----------
__global__ __launch_bounds__(256) void cvt_v_kernel(
    const float* __restrict__ in, unsigned short* __restrict__ out) {
  __shared__ float t[64][33];
  int s0 = blockIdx.x * 64, d0 = blockIdx.y * 32, g = blockIdx.z;
  int tid = threadIdx.x;
#pragma unroll
  for (int p = 0; p < 2; ++p) {
    int idx = p * 256 + tid;
    int s = idx >> 3, dq = (idx & 7) * 4;
    float4 v = *reinterpret_cast<const float4*>(
        in + ((size_t)(s0 + s) * G_ + g) * D_ + d0 + dq);
    t[s][dq] = v.x; t[s][dq + 1] = v.y; t[s][dq + 2] = v.z; t[s][dq + 3] = v.w;
  }
  __syncthreads();
  int d = tid >> 3, sq = (tid & 7) * 8;
  bf16x8 o;
#pragma unroll
  for (int j = 0; j < 8; ++j) o[j] = f2bf(t[sq + j][d]);
  *reinterpret_cast<bf16x8*>(out + ((size_t)g * D_ + d0 + d) * S_ + s0 + sq) = o;
}

// ---------------- flash attention, 32x32 MFMA, swapped operands ----------------
// grid (S/128, H), 4 waves/block, wave owns 32 q-rows (lane&31 = q).
// S^T[kv][q] = K·Q^T  (A = K from LDS, B = Q in regs)
// O^T[d][q] += Vt·P^T (A = Vt from LDS, B = P in regs via permlane32_swap)
// 3-buffer LDS pipeline, counted vmcnt(4) + raw s_barrier (one per tile).
constexpr int QB2 = 128, KVB = 32, NT = S_ / KVB;
constexpr float RTHR = 8.0f;   // defer-max threshold (T13)

__global__ __launch_bounds__(256, 2) void attn32_kernel(
    const float* __restrict__ q, const unsigned short* __restrict__ kb,
    const unsigned short* __restrict__ vtb, unsigned short* __restrict__ aout) {
  // 3 buffers x (K 8KB + V 8KB) = 48KB; epilogue reuses first 32KB.
  __shared__ __align__(16) char smem[49152];

  const int qt = blockIdx.x, h = blockIdx.y;
  const int g = h >> 2;   // HPG = 4
  const int tid = threadIdx.x, w = tid >> 6, lane = tid & 63;
  const int l31 = lane & 31, hi = lane >> 5;

  // ---- Q B-frags (scaled, cvt once per block): qf[c] d = c*16 + hi*8 + e ----
  const float scale = 0.08838834764831845f;
  bf16x8 qf[8];
  const int qrow = qt * QB2 + w * 32 + l31;
  {
    const float* qp = q + ((size_t)qrow * H_ + h) * D_;
#pragma unroll
    for (int c = 0; c < 8; ++c) {
      const float* p0 = qp + c * 16 + hi * 8;
      float4 a = *(const float4*)p0;
      float4 b = *(const float4*)(p0 + 4);
      bf16x8 f;
      f[0] = f2bf(a.x * scale); f[1] = f2bf(a.y * scale);
      f[2] = f2bf(a.z * scale); f[3] = f2bf(a.w * scale);
      f[4] = f2bf(b.x * scale); f[5] = f2bf(b.y * scale);
      f[6] = f2bf(b.z * scale); f[7] = f2bf(b.w * scale);
      qf[c] = f;
    }
  }

  // ---- staging source precompute (pre-swizzled so linear LDS == swizzled) ----
  // K phys byte p: row kv = p>>8, logical col byte = (p&255) ^ ((kv&7)<<4)
  // V phys byte p: row d  = p>>6, logical col byte = (p&63) ^ (((d>>1)&3)<<4)
  int ks_kv[2], ks_d[2], vs_d[2], vs_kv[2];
#pragma unroll
  for (int hh = 0; hh < 2; ++hh) {
    int p = w * 1024 + hh * 4096 + lane * 16;
    int kvr = p >> 8;
    ks_kv[hh] = kvr;
    ks_d[hh] = ((p & 255) ^ ((kvr & 7) << 4)) >> 1;
    int dr = p >> 6;
    vs_d[hh] = dr;
    vs_kv[hh] = ((p & 63) ^ (((dr >> 1) & 3) << 4)) >> 1;
  }
  const unsigned short* kg = kb + (size_t)g * S_ * D_;
  const unsigned short* vg = vtb + (size_t)g * D_ * S_;

  auto stage = [&](int t, int buf) {
    int kv0 = t * KVB;
    char* Kd = smem + buf * 16384;
    char* Vd = smem + buf * 16384 + 8192;
#pragma unroll
    for (int hh = 0; hh < 2; ++hh) {
      gload_lds16(kg + (size_t)(kv0 + ks_kv[hh]) * D_ + ks_d[hh],
                  Kd + w * 1024 + hh * 4096);
      gload_lds16(vg + (size_t)vs_d[hh] * S_ + kv0 + vs_kv[hh],
                  Vd + w * 1024 + hh * 4096);
    }
  };

  f32x16 of[4];
#pragma unroll
  for (int i = 0; i < 4; ++i) of[i] = (f32x16)0.f;
  float m = -1e30f, l = 0.f;

  stage(0, 0);
  stage(1, 1);

  for (int t = 0; t < NT; ++t) {
    const int buf = t % 3;
    // counted wait: 4 newest (stage t+1) may stay in flight; last iter drains.
    if (t + 1 < NT) asm volatile("s_waitcnt vmcnt(4)" ::: "memory");
    else            asm volatile("s_waitcnt vmcnt(0)" ::: "memory");
    __builtin_amdgcn_s_barrier();
    if (t + 2 < NT) stage(t + 2, (t + 2) % 3);

    const char* Kd = smem + buf * 16384;
    const char* Vd = smem + buf * 16384 + 8192;

    // ---- QK^T: S^T[kv][q], two independent 4-chains ----
    f32x16 s0 = (f32x16)0.f, s1 = (f32x16)0.f;
    __builtin_amdgcn_s_setprio(1);
#pragma unroll
    for (int c = 0; c < 8; ++c) {
      unsigned off = ((unsigned)(l31 * 256 + c * 32 + hi * 16)) ^
                     ((unsigned)(l31 & 7) << 4);
      bf16x8 kf = *(const bf16x8*)(Kd + off);
      if (c & 1)
        s1 = __builtin_amdgcn_mfma_f32_32x32x16_bf16(kf, qf[c], s1, 0, 0, 0);
      else
        s0 = __builtin_amdgcn_mfma_f32_32x32x16_bf16(kf, qf[c], s0, 0, 0, 0);
    }
    __builtin_amdgcn_s_setprio(0);
    f32x16 sv = s0 + s1;   // S rows: kv = (r&3) + 8*(r>>2) + 4*hi; col q = l31

    // ---- online softmax (per-lane q; halves share q via lane^32) ----
    float tmax = sv[0];
#pragma unroll
    for (int r = 1; r < 16; ++r) tmax = fmaxf(tmax, sv[r]);
    tmax = fmaxf(tmax, __shfl_xor(tmax, 32));
    if (__any(tmax > m + RTHR)) {
      float mnew = fmaxf(m, tmax);
      float alpha = __expf(m - mnew);
#pragma unroll
      for (int i = 0; i < 4; ++i)
#pragma unroll
        for (int r = 0; r < 16; ++r) of[i][r] *= alpha;
      l *= alpha;
      m = mnew;
    }
    float pv[16];
    float sum = 0.f;
#pragma unroll
    for (int r = 0; r < 16; ++r) { pv[r] = __expf(sv[r] - m); sum += pv[r]; }
    sum += __shfl_xor(sum, 32);
    l += sum;

    // ---- P -> B-frags: cvt_pk pairs, permlane32_swap gathers lows/highs ----
    unsigned pk[8];
#pragma unroll
    for (int b = 0; b < 8; ++b) pk[b] = cvt_pk_bf16(pv[2 * b], pv[2 * b + 1]);
    bf16x8 pf[2];
#pragma unroll
    for (int kc = 0; kc < 2; ++kc) {
      auto sA = __builtin_amdgcn_permlane32_swap(pk[kc * 4 + 0], pk[kc * 4 + 2],
                                                 false, false);
      auto sB = __builtin_amdgcn_permlane32_swap(pk[kc * 4 + 1], pk[kc * 4 + 3],
                                                 false, false);
      unsigned fr[4] = {(unsigned)sA[0], (unsigned)sB[0],
                        (unsigned)sA[1], (unsigned)sB[1]};
      __builtin_memcpy(&pf[kc], fr, 16);
    }

    // ---- PV: O^T[d][q] += Vt·P^T, 4 independent chains ----
    __builtin_amdgcn_s_setprio(1);
#pragma unroll
    for (int db = 0; db < 4; ++db) {
      int d = db * 32 + l31;
#pragma unroll
      for (int kc = 0; kc < 2; ++kc) {
        unsigned off = ((unsigned)(d * 64 + kc * 32 + hi * 16)) ^
                       ((unsigned)((d >> 1) & 3) << 4);
        bf16x8 vf = *(const bf16x8*)(Vd + off);
        of[db] = __builtin_amdgcn_mfma_f32_32x32x16_bf16(vf, pf[kc], of[db], 0, 0, 0);
      }
    }
    __builtin_amdgcn_s_setprio(0);
  }

  // ---- epilogue: normalize, transpose via LDS, coalesced bf16 store ----
  __syncthreads();   // all waves done with PV reads before Ol overwrites bufs
  float inv = 1.0f / l;
  unsigned short* Ol = (unsigned short*)smem;   // [128 q][128 d] bf16 = 32KB
  const int ql = w * 32 + l31;
#pragma unroll
  for (int db = 0; db < 4; ++db) {
#pragma unroll
    for (int rp = 0; rp < 8; ++rp) {
      int r0 = rp * 2;
      int d0 = db * 32 + (r0 & 3) + 8 * (r0 >> 2) + 4 * hi;  // d0 even, d0+1 next
      unsigned pkv = cvt_pk_bf16(of[db][r0] * inv, of[db][r0 + 1] * inv);
      unsigned off = ((unsigned)(ql * 256 + d0 * 2)) ^ ((unsigned)(ql & 7) << 4);
      *(unsigned*)((char*)Ol + off) = pkv;
    }
  }
  __syncthreads();
  const size_t obase = ((size_t)qt * QB2) * MODEL_ + (size_t)h * D_;
#pragma unroll
  for (int pass = 0; pass < 8; ++pass) {
    int row = pass * 16 + (tid >> 4);
    int c = tid & 15;
    unsigned off = ((unsigned)(row * 256 + c * 16)) ^ ((unsigned)(row & 7) << 4);
    bf16x8 vv = *(const bf16x8*)((char*)Ol + off);
    *(bf16x8*)(aout + obase + (size_t)row * MODEL_ + c * 8) = vv;
  }
}

// ---------------- out-projection GEMM: C = A @ B^T + bias (m97 structure) ----
constexpr int BM = 128, BN = 128, BK = 64;

__global__ __launch_bounds__(256, 2) void gemm_bt_bias(
    const unsigned short* __restrict__ A, const unsigned short* __restrict__ B,
    const float* __restrict__ bias, float* __restrict__ C) {
  __shared__ unsigned short As[BM * BK];
  __shared__ unsigned short Bs[BN * BK];

  const int tid = threadIdx.x;
  const int w = tid >> 6, lane = tid & 63;
  const int wr = w >> 1, wc = w & 1;
  const int r16 = lane & 15, g4 = lane >> 4;
  const int row0 = blockIdx.y * BM, col0 = blockIdx.x * BN;

  f32x4 acc[4][4];
#pragma unroll
  for (int m = 0; m < 4; ++m)
#pragma unroll
    for (int n = 0; n < 4; ++n) acc[m][n] = (f32x4)0.f;

  for (int kt = 0; kt < MODEL_ / BK; ++kt) {
    const int k0 = kt * BK;
    __syncthreads();
#pragma unroll
    for (int j = 0; j < 4; ++j) {
      int chunk = w * 4 + j;
      int sb = chunk * 1024 + lane * 16;
      int srow = sb >> 7;
      int lb = sb ^ ((srow & 7) << 4);
      int kk = (lb & 127) >> 1;
      gload_lds16(A + (size_t)(row0 + srow) * MODEL_ + k0 + kk,
                  (char*)As + chunk * 1024);
      gload_lds16(B + (size_t)(col0 + srow) * MODEL_ + k0 + kk,
                  (char*)Bs + chunk * 1024);
    }
    asm volatile("s_waitcnt vmcnt(0)" ::: "memory");
    __syncthreads();

#pragma unroll
    for (int kc = 0; kc < 2; ++kc) {
      bf16x8 af[4], bfr[4];
#pragma unroll
      for (int m = 0; m < 4; ++m) {
        int row = wr * 64 + m * 16 + r16;
        unsigned off = ((unsigned)(row * 128 + (kc * 32 + g4 * 8) * 2)) ^ ((row & 7) << 4);
        af[m] = *(bf16x8*)((char*)As + off);
      }
#pragma unroll
      for (int n = 0; n < 4; ++n) {
        int row = wc * 64 + n * 16 + r16;
        unsigned off = ((unsigned)(row * 128 + (kc * 32 + g4 * 8) * 2)) ^ ((row & 7) << 4);
        bfr[n] = *(bf16x8*)((char*)Bs + off);
      }
#pragma unroll
      for (int m = 0; m < 4; ++m)
#pragma unroll
        for (int n = 0; n < 4; ++n)
          acc[m][n] = __builtin_amdgcn_mfma_f32_16x16x32_bf16(af[m], bfr[n], acc[m][n], 0, 0, 0);
    }
  }

#pragma unroll
  for (int n = 0; n < 4; ++n) {
    int col = col0 + wc * 64 + n * 16 + r16;
    float bv = bias[col];
#pragma unroll
    for (int m = 0; m < 4; ++m) {
      int rbase = row0 + wr * 64 + m * 16 + g4 * 4;
#pragma unroll
      for (int j = 0; j < 4; ++j)
        C[(size_t)(rbase + j) * MODEL_ + col] = acc[m][n][j] + bv;
    }
  }
}

extern "C" void kernel_launch(void* const* d_in, const int* in_sizes, int n_in,
                              void* d_out, int out_size, void* d_ws, size_t ws_size,
                              hipStream_t stream) {
  const float* q = (const float*)d_in[0];
  const float* k = (const float*)d_in[1];
  const float* v = (const float*)d_in[2];
  // d_in[3] = mask: faithfully unused (reference never applies it)
  const float* w_out = (const float*)d_in[4];
  const float* b_out = (const float*)d_in[5];
  float* out = (float*)d_out;

  // ws layout: [attn_bf 16.78MB][X region 33.55MB]
  //   X holds k_bf(4MB)+vt_bf(4MB) during attention, then w_bf (cvt AFTER attn).
  unsigned short* attn_bf = (unsigned short*)d_ws;
  unsigned short* xreg = attn_bf + (size_t)S_ * MODEL_;
  unsigned short* k_bf = xreg;
  unsigned short* vt_bf = xreg + (size_t)G_ * S_ * D_;
  unsigned short* w_bf = xreg;
  if (ws_size < ((size_t)S_ * MODEL_ + (size_t)MODEL_ * MODEL_) * 2) return;

  cvt_k_kernel<<<S_ * G_ * D_ / 4 / 256, 256, 0, stream>>>(k, k_bf);
  dim3 vg(S_ / 64, D_ / 32, G_);
  cvt_v_kernel<<<vg, 256, 0, stream>>>(v, vt_bf);

  dim3 ag(S_ / QB2, H_);
  attn32_kernel<<<ag, 256, 0, stream>>>(q, k_bf, vt_bf, attn_bf);

  cvt_f32_to_bf16<<<(MODEL_ * MODEL_ / 4) / 256, 256, 0, stream>>>(
      w_out, w_bf, MODEL_ * MODEL_ / 4);

  dim3 gg(MODEL_ / BN, S_ / BM);
  gemm_bt_bias<<<gg, 256, 0, stream>>>(attn_bf, w_bf, b_out, out);
}